// Round 7
// baseline (371.461 us; speedup 1.0000x reference)
//
#include <hip/hip_runtime.h>

typedef unsigned short ushort_t;
typedef float f32x4 __attribute__((ext_vector_type(4)));
typedef short short8 __attribute__((ext_vector_type(8)));

#define B_   32
#define C_   1536
#define N_   576      // H*W = 24*24
#define HID_ 512
#define D_   128
#define K_   64

__device__ __forceinline__ float bf2f(ushort_t u) {
    union { unsigned u; float f; } c; c.u = ((unsigned)u) << 16; return c.f;
}
__device__ __forceinline__ ushort_t f2bf(float x) {
    unsigned u = __float_as_uint(x);
    return (ushort_t)((u + 0x7FFFu + ((u >> 16) & 1u)) >> 16);
}

// async global->LDS, 16B per lane. LDS dest = wave-uniform base + lane*16.
typedef const __attribute__((address_space(1))) char gas_char;
typedef __attribute__((address_space(3))) char las_char;
__device__ __forceinline__ void cp16(const void* g, void* l) {
    __builtin_amdgcn_global_load_lds((gas_char*)(size_t)g,
                                     (las_char*)(unsigned)(size_t)l, 16, 0, 0);
}
// raw barrier with compile-time memory fences (no vmcnt/lgkm drain!)
__device__ __forceinline__ void bar() {
    asm volatile("" ::: "memory");
    __builtin_amdgcn_s_barrier();
    asm volatile("" ::: "memory");
}

// Wb layout: W1cat (1024,1536) = [w1c;w1s] | b1cat (1024) | w2c | b2c | w2s | b2s
#define OB1_  1572864
#define OW2C_ 1573888
#define OB2C_ 1639424
#define OW2S_ 1639552
#define OB2S_ 1672320
#define WTOT_ 1672384
#define TRB2_ 3456                       // 12*9*32 transpose blocks (128c x 64n)
#define CVB4_ (((WTOT_ / 4) + 255) / 256)

// ---------------------------------------------------------------- prep
// Transpose x (B,C,N) -> Xt (B,N,C) bf16 with 128(C)x64(N) tiles.
__global__ __launch_bounds__(256) void prep_kernel(
    const void* __restrict__ x,
    const void* __restrict__ w1c, const void* __restrict__ b1c,
    const void* __restrict__ w2c, const void* __restrict__ b2c,
    const void* __restrict__ w1s, const void* __restrict__ b1s,
    const void* __restrict__ w2s, const void* __restrict__ b2s,
    const unsigned* __restrict__ temp,
    ushort_t* __restrict__ xt, ushort_t* __restrict__ o, float* __restrict__ Tp)
{
    __shared__ ushort_t t[128][65];
    unsigned d = temp[0];
    int flag = (d == 0x3F800000u) ? 1 : 0;
    int tid = threadIdx.x;
    int idx = blockIdx.x;
    if (idx == 0 && tid == 0)
        *Tp = flag ? __uint_as_float(d) : bf2f((ushort_t)(d & 0xFFFFu));

    if (idx < TRB2_) {
        int b = idx / 108, rem = idx % 108;
        int c0 = (rem % 12) * 128, n0 = (rem / 12) * 64;
        ushort_t* xtb = xt + (size_t)b * N_ * C_;
        int r = tid >> 4, n4 = (tid & 15) * 4;
        if (flag) {
            const float* xb = (const float*)x + (size_t)b * C_ * N_;
#pragma unroll
            for (int i = 0; i < 8; ++i) {
                int cc = r + i * 16;
                float4 v = *(const float4*)&xb[(size_t)(c0 + cc) * N_ + n0 + n4];
                t[cc][n4 + 0] = f2bf(v.x);
                t[cc][n4 + 1] = f2bf(v.y);
                t[cc][n4 + 2] = f2bf(v.z);
                t[cc][n4 + 3] = f2bf(v.w);
            }
        } else {
            const ushort_t* xb = (const ushort_t*)x + (size_t)b * C_ * N_;
#pragma unroll
            for (int i = 0; i < 8; ++i) {
                int cc = r + i * 16;
                *(uint2*)&t[cc][n4] =
                    *(const uint2*)&xb[(size_t)(c0 + cc) * N_ + n0 + n4];
            }
        }
        __syncthreads();
        int c8 = (tid & 15) * 8;
#pragma unroll
        for (int i = 0; i < 4; ++i) {
            int nn = r + i * 16;
            ushort_t vv[8];
#pragma unroll
            for (int j = 0; j < 8; ++j) vv[j] = t[c8 + j][nn];
            uint4 o4;
            o4.x = (unsigned)vv[0] | ((unsigned)vv[1] << 16);
            o4.y = (unsigned)vv[2] | ((unsigned)vv[3] << 16);
            o4.z = (unsigned)vv[4] | ((unsigned)vv[5] << 16);
            o4.w = (unsigned)vv[6] | ((unsigned)vv[7] << 16);
            *(uint4*)&xtb[(size_t)(n0 + nn) * C_ + c0 + c8] = o4;
        }
    } else {
        int i4 = ((idx - TRB2_) * 256 + tid) * 4;
        if (i4 >= WTOT_) return;
        const void* p; int off;
        if      (i4 < 786432)  { p = w1c; off = i4; }
        else if (i4 < OB1_)    { p = w1s; off = i4 - 786432; }
        else if (i4 < 1573376) { p = b1c; off = i4 - OB1_; }
        else if (i4 < OW2C_)   { p = b1s; off = i4 - 1573376; }
        else if (i4 < OB2C_)   { p = w2c; off = i4 - OW2C_; }
        else if (i4 < OW2S_)   { p = b2c; off = i4 - OB2C_; }
        else if (i4 < OB2S_)   { p = w2s; off = i4 - OW2S_; }
        else                   { p = b2s; off = i4 - OB2S_; }
        if (flag) {
            float4 v = *(const float4*)((const float*)p + off);
            uint2 r;
            r.x = (unsigned)f2bf(v.x) | ((unsigned)f2bf(v.y) << 16);
            r.y = (unsigned)f2bf(v.z) | ((unsigned)f2bf(v.w) << 16);
            *(uint2*)&o[i4] = r;
        } else {
            *(uint2*)&o[i4] = *(const uint2*)((const ushort_t*)p + off);
        }
    }
}

// ---------------------------------------------------------------- gemm1
// Round-4 proven skeleton (256 thr, 4 waves 2x2, 2-phase dbuf, counted
// vmcnt, two barriers) with ONE change: B is no longer LDS-staged.
// B fragments (16B/lane contiguous along K in row-major W1) load
// global->VGPR, double-buffered (bfr[2][2][4]). LDS traffic per K-step
// 96KB -> 48KB (A write 16 + A reads 32); B reuse (2 waves share cols)
// served by L1/L2. vmcnt(12) = 4 cp16 + 8 B-loads of the next tile stay
// in flight across the barrier. LDS/block 32KB.
__global__ __launch_bounds__(256) void gemm1_kernel(
    const ushort_t* __restrict__ Xt, const ushort_t* __restrict__ W1,
    const ushort_t* __restrict__ bias, ushort_t* __restrict__ h)
{
    __shared__ ushort_t Atile[2][128 * 64];   // 16 KB each
    int idx = blockIdx.x;
    int l = (idx & 7) * 144 + (idx >> 3);    // XCD-chunked logical id
    int mt = l >> 3, t = l & 7;
    int row0 = mt * 128, col0 = t * 128;

    int tid = threadIdx.x, w = tid >> 6, lane = tid & 63;
    int wr = w >> 1, wc = w & 1;
    int r16 = lane & 15, q = lane >> 4, kh = q * 8;

    int srow = tid >> 3;
    int cx = ((tid & 7) ^ (srow & 7)) * 8;   // pre-swizzled source col (elems)
    const ushort_t* ag[4];
#pragma unroll
    for (int s = 0; s < 4; ++s)
        ag[s] = Xt + (size_t)(row0 + s * 32 + srow) * C_ + cx;

    // per-wave B fragment pointers: col = col0 + wc*64 + j*16 + r16, k = kh
    const ushort_t* bgp[4];
#pragma unroll
    for (int j = 0; j < 4; ++j)
        bgp[j] = W1 + (size_t)(col0 + wc * 64 + j * 16 + r16) * C_ + kh;

    f32x4 acc[4][4];
#pragma unroll
    for (int i = 0; i < 4; ++i)
#pragma unroll
        for (int j = 0; j < 4; ++j) acc[i][j] = f32x4{0.f, 0.f, 0.f, 0.f};

    short8 bfr[2][2][4];                     // [buf][ks][j], 64 VGPR

    int rowa = wr * 64 + r16;
    int xr = (r16 & 7) * 8;                  // read-side XOR (elems)

    auto stageA = [&](int buf, int koff) {
#pragma unroll
        for (int s = 0; s < 4; ++s)
            cp16(ag[s] + koff, &Atile[buf][tid * 8 + s * 2048]);
    };
    auto loadB = [&](int buf, int koff) {
#pragma unroll
        for (int ks = 0; ks < 2; ++ks)
#pragma unroll
            for (int j = 0; j < 4; ++j)
                bfr[buf][ks][j] = *(const short8*)(bgp[j] + koff + ks * 32);
    };
    auto compute = [&](int cb) {
#pragma unroll
        for (int ks = 0; ks < 2; ++ks) {
            int ke = (ks * 32 + kh) ^ xr;
            short8 af[4];
#pragma unroll
            for (int i = 0; i < 4; ++i)
                af[i] = *(const short8*)&Atile[cb][(rowa + i * 16) * 64 + ke];
#pragma unroll
            for (int i = 0; i < 4; ++i)
#pragma unroll
                for (int j = 0; j < 4; ++j)
                    acc[i][j] = __builtin_amdgcn_mfma_f32_16x16x32_bf16(
                        af[i], bfr[cb][ks][j], acc[i][j], 0, 0, 0);
        }
    };

    stageA(0, 0);
    loadB(0, 0);
#pragma unroll
    for (int kt = 0; kt < 24; ++kt) {
        int buf = kt & 1;
        if (kt < 23) {
            stageA(buf ^ 1, (kt + 1) * 64);
            loadB(buf ^ 1, (kt + 1) * 64);
            asm volatile("s_waitcnt vmcnt(12)" ::: "memory");
        } else {
            asm volatile("s_waitcnt vmcnt(0)" ::: "memory");
        }
        bar();
        compute(buf);
        bar();
    }

#pragma unroll
    for (int j = 0; j < 4; ++j) {
        int col = col0 + wc * 64 + j * 16 + r16;
        float cb = bf2f(bias[col]);
#pragma unroll
        for (int i = 0; i < 4; ++i) {
            int rowo = row0 + wr * 64 + i * 16 + q * 4;
#pragma unroll
            for (int r = 0; r < 4; ++r) {
                float v = fmaxf(acc[i][j][r] + cb, 0.f);
                h[(size_t)(rowo + r) * 1024 + col] = f2bf(v);
            }
        }
    }
}

// ---------------------------------------------------------------- gemm2
// 2-phase pipeline, BK=32, 16 K-steps fully unrolled, vmcnt(4).
__global__ __launch_bounds__(256) void gemm2_kernel(
    const ushort_t* __restrict__ Wb, const ushort_t* __restrict__ h,
    ushort_t* __restrict__ fbuf, float* __restrict__ sbuf)
{
    __shared__ ushort_t Atile[2][128 * 32];
    __shared__ ushort_t Btile[2][128 * 32];
    int nt = blockIdx.x, b = blockIdx.y, z = blockIdx.z;
    int col0 = nt * 128;
    int Mclamp = z ? K_ : D_;
    const ushort_t* Aw   = Wb + (z ? OW2S_ : OW2C_);
    const ushort_t* bias = Wb + (z ? OB2S_ : OB2C_);
    const ushort_t* hb = h + (size_t)b * N_ * 1024 + (z ? 512 : 0);

    int tid = threadIdx.x, w = tid >> 6, lane = tid & 63;
    int wr = w >> 1, wc = w & 1;
    int r16 = lane & 15, q = lane >> 4, kh = q * 8;

    int srow = tid >> 2;
    int swz = ((tid & 3) ^ (srow & 3)) * 8;
    int ar0 = min(srow, Mclamp - 1);
    int ar1 = min(64 + srow, Mclamp - 1);
    const ushort_t* ag0 = Aw + (size_t)ar0 * HID_ + swz;
    const ushort_t* ag1 = Aw + (size_t)ar1 * HID_ + swz;
    int br0 = min(col0 + srow, N_ - 1);
    int br1 = min(col0 + 64 + srow, N_ - 1);
    const ushort_t* bg0 = hb + (size_t)br0 * 1024 + swz;
    const ushort_t* bg1 = hb + (size_t)br1 * 1024 + swz;

    f32x4 acc[4][4];
#pragma unroll
    for (int i = 0; i < 4; ++i)
#pragma unroll
        for (int j = 0; j < 4; ++j) acc[i][j] = f32x4{0.f, 0.f, 0.f, 0.f};

    int xr = (r16 & 3) * 8;

    auto stage = [&](int buf, int koff) {
        cp16(ag0 + koff, &Atile[buf][tid * 8]);
        cp16(ag1 + koff, &Atile[buf][2048 + tid * 8]);
        cp16(bg0 + koff, &Btile[buf][tid * 8]);
        cp16(bg1 + koff, &Btile[buf][2048 + tid * 8]);
    };
    auto compute = [&](int cb) {
        int ke = kh ^ xr;
        short8 af[4], bf[4];
#pragma unroll
        for (int i = 0; i < 4; ++i)
            af[i] = *(const short8*)&Atile[cb][(wr * 64 + i * 16 + r16) * 32 + ke];
#pragma unroll
        for (int j = 0; j < 4; ++j)
            bf[j] = *(const short8*)&Btile[cb][(wc * 64 + j * 16 + r16) * 32 + ke];
#pragma unroll
        for (int i = 0; i < 4; ++i)
#pragma unroll
            for (int j = 0; j < 4; ++j)
                acc[i][j] = __builtin_amdgcn_mfma_f32_16x16x32_bf16(
                    af[i], bf[j], acc[i][j], 0, 0, 0);
    };

    stage(0, 0);
#pragma unroll
    for (int kt = 0; kt < 16; ++kt) {
        int buf = kt & 1;
        if (kt < 15) {
            stage(buf ^ 1, (kt + 1) * 32);
            asm volatile("s_waitcnt vmcnt(4)" ::: "memory");
        } else {
            asm volatile("s_waitcnt vmcnt(0)" ::: "memory");
        }
        bar();
        compute(buf);
        bar();
    }

#pragma unroll
    for (int j = 0; j < 4; ++j) {
        int col = col0 + wc * 64 + j * 16 + r16;
#pragma unroll
        for (int i = 0; i < 4; ++i) {
            int rowb = wr * 64 + i * 16 + q * 4;
#pragma unroll
            for (int r = 0; r < 4; ++r) {
                int rr = rowb + r;
                if (rr < Mclamp && col < N_) {
                    float v = acc[i][j][r] + bf2f(bias[rr]);
                    if (z == 0)
                        fbuf[(size_t)b * D_ * N_ + (size_t)rr * N_ + col] = f2bf(v);
                    else
                        sbuf[(size_t)b * K_ * N_ + (size_t)rr * N_ + col] = v;
                }
            }
        }
    }
}

// ---------------------------------------------------------------- tail
// One block per batch (512 thr). Fused sinkhorn + aggregation + L2 norm.
__global__ __launch_bounds__(512) void tail_kernel(
    const ushort_t* __restrict__ f_all, const float* __restrict__ s_all,
    const float* __restrict__ Tp, const unsigned* __restrict__ temp,
    void* __restrict__ out)
{
    __shared__ float Sl[K_ * 577];   // 147,712 B
    __shared__ float su[K_];
    __shared__ float sv[N_];
    __shared__ float red[8];
    ushort_t* Plds = (ushort_t*)Sl;                       // [0, 74,752)
    ushort_t* At0  = (ushort_t*)((char*)Sl + 81920);      // 16 KB
    ushort_t* At1  = (ushort_t*)((char*)Sl + 81920 + 16384);

    int b = blockIdx.x;
    int tid = threadIdx.x, w = tid >> 6, lane = tid & 63;
    const float norm = -logf((float)N_);

    // ---- load S into LDS (coalesced float4)
    const float4* S4 = (const float4*)(s_all + (size_t)b * K_ * N_);
    for (int g = tid; g < (K_ * N_) / 4; g += 512) {
        float4 v = S4[g];
        int w0 = g * 4;
        int r = w0 / N_;
        int base = w0 + r;           // == r*577 + (w0 - r*576)
        Sl[base + 0] = v.x; Sl[base + 1] = v.y;
        Sl[base + 2] = v.z; Sl[base + 3] = v.w;
    }
    for (int n = tid; n < N_; n += 512) sv[n] = 0.f;
    __syncthreads();

    // ---- 3 sinkhorn iterations
    for (int it = 0; it < 3; ++it) {
        for (int r = w; r < K_; r += 8) {
            const float* Sr = Sl + r * 577;
            float a0 = 0.f, a1 = 0.f, a2 = 0.f;
#pragma unroll
            for (int k = 0; k < 9; k += 3) {
                int n0 = lane + 64 * k;
                a0 += __expf(Sr[n0] + sv[n0]);
                a1 += __expf(Sr[n0 + 64] + sv[n0 + 64]);
                a2 += __expf(Sr[n0 + 128] + sv[n0 + 128]);
            }
            float t = a0 + a1 + a2;
#pragma unroll
            for (int off = 32; off; off >>= 1) t += __shfl_xor(t, off);
            if (lane == 0) su[r] = norm - __logf(t);
        }
        __syncthreads();
        for (int n = tid; n < N_; n += 512) {
            const float* Sc = Sl + n;
            float a0 = 0.f, a1 = 0.f, a2 = 0.f, a3 = 0.f;
#pragma unroll
            for (int m = 0; m < K_; m += 4) {
                a0 += __expf(Sc[(m + 0) * 577] + su[m + 0]);
                a1 += __expf(Sc[(m + 1) * 577] + su[m + 1]);
                a2 += __expf(Sc[(m + 2) * 577] + su[m + 2]);
                a3 += __expf(Sc[(m + 3) * 577] + su[m + 3]);
            }
            sv[n] = norm - __logf((a0 + a1) + (a2 + a3));
        }
        __syncthreads();
    }

    // ---- P into regs (wave w owns rows 8w..8w+7), barrier, pack into LDS
    float invT = 1.f / (*Tp);
    ushort_t pv[8][9];
#pragma unroll
    for (int rr = 0; rr < 8; ++rr) {
        int r = w * 8 + rr;
        float ur = su[r];
        const float* Sr = Sl + r * 577;
#pragma unroll
        for (int k = 0; k < 9; ++k) {
            int n0 = lane + 64 * k;
            float lp = Sr[n0] + ur + sv[n0] - norm;
            pv[rr][k] = f2bf(__expf(lp * invT) + __expf(lp));
        }
    }
    __syncthreads();   // all S reads complete before overwriting with P
#pragma unroll
    for (int rr = 0; rr < 8; ++rr) {
        int r = w * 8 + rr;
#pragma unroll
        for (int k = 0; k < 9; ++k)
            Plds[r * 584 + lane + 64 * k] = pv[rr][k];
    }
    __syncthreads();   // P visible to all waves (full lgkm drain)

    // ---- agg GEMM: 9 steps BK=64, dbuf F staging, P in place
    int wr = w >> 2, wc = w & 3;
    int r16 = lane & 15, q = lane >> 4, kh = q * 8;
    const ushort_t* F = f_all + (size_t)b * D_ * N_;
    int srow = tid >> 3;                      // 0..63
    int cx = ((tid & 7) ^ (srow & 7)) * 8;    // pre-swizzled source col
    const ushort_t* fg0 = F + (size_t)srow * N_ + cx;
    const ushort_t* fg1 = F + (size_t)(64 + srow) * N_ + cx;

    f32x4 acc[4];
#pragma unroll
    for (int i = 0; i < 4; ++i) acc[i] = f32x4{0.f, 0.f, 0.f, 0.f};

    int rowa = wr * 64 + r16;
    int prow = wc * 16 + r16;
    int xr = (r16 & 7) * 8;

    auto stageF = [&](ushort_t* At, int koff) {
        cp16(fg0 + koff, At + tid * 8);
        cp16(fg1 + koff, At + 4096 + tid * 8);
    };
    auto computeT = [&](const ushort_t* At, int s) {
#pragma unroll
        for (int ks = 0; ks < 2; ++ks) {
            int ke = (ks * 32 + kh) ^ xr;
            short8 af[4];
#pragma unroll
            for (int i = 0; i < 4; ++i)
                af[i] = *(const short8*)&At[(rowa + i * 16) * 64 + ke];
            short8 pf = *(const short8*)&Plds[prow * 584 + s * 64 + ks * 32 + kh];
#pragma unroll
            for (int i = 0; i < 4; ++i)
                acc[i] = __builtin_amdgcn_mfma_f32_16x16x32_bf16(
                    af[i], pf, acc[i], 0, 0, 0);
        }
    };

    stageF(At0, 0);
#pragma unroll
    for (int kt = 0; kt < 9; ++kt) {
        ushort_t* cb = (kt & 1) ? At1 : At0;
        ushort_t* nb = (kt & 1) ? At0 : At1;
        if (kt < 8) {
            stageF(nb, (kt + 1) * 64);
            asm volatile("s_waitcnt vmcnt(2)" ::: "memory");
        } else {
            asm volatile("s_waitcnt vmcnt(0)" ::: "memory");
        }
        bar();
        computeT(cb, kt);
        bar();
    }

    // ---- block-wide L2 norm + store
    float ssq = 0.f;
#pragma unroll
    for (int i = 0; i < 4; ++i)
#pragma unroll
        for (int r = 0; r < 4; ++r) { float v = acc[i][r]; ssq += v * v; }
#pragma unroll
    for (int off = 32; off; off >>= 1) ssq += __shfl_xor(ssq, off);
    if (lane == 0) red[w] = ssq;
    __syncthreads();
    float tot = (red[0] + red[1] + red[2] + red[3])
              + (red[4] + red[5] + red[6] + red[7]);
    float inv = 1.f / fmaxf(sqrtf(tot), 1e-12f);
    int flag = (temp[0] == 0x3F800000u) ? 1 : 0;
#pragma unroll
    for (int i = 0; i < 4; ++i) {
        int col = wc * 16 + r16;
#pragma unroll
        for (int r = 0; r < 4; ++r) {
            int row = wr * 64 + i * 16 + q * 4 + r;
            float v = acc[i][r] * inv;
            size_t idx = (size_t)b * D_ * K_ + (size_t)row * K_ + col;
            if (flag) ((float*)out)[idx] = v;
            else      ((ushort_t*)out)[idx] = f2bf(v);
        }
    }
}

extern "C" void kernel_launch(void* const* d_in, const int* in_sizes, int n_in,
                              void* d_out, int out_size, void* d_ws, size_t ws_size,
                              hipStream_t stream) {
    const void* x    = d_in[0];
    const void* w1c  = d_in[1];
    const void* b1c  = d_in[2];
    const void* w2c  = d_in[3];
    const void* b2c  = d_in[4];
    const void* w1s  = d_in[5];
    const void* b1s  = d_in[6];
    const void* w2s  = d_in[7];
    const void* b2s  = d_in[8];
    const unsigned* temp = (const unsigned*)d_in[9];

    char* ws = (char*)d_ws;
    float* Tp = (float*)ws;
    ushort_t* Wb = (ushort_t*)(ws + 256);
    size_t offXt = 256 + (((size_t)WTOT_ * 2 + 255) & ~(size_t)255);
    ushort_t* Xt = (ushort_t*)(ws + offXt);
    size_t xtBytes = (size_t)B_ * N_ * C_ * 2;
    ushort_t* h  = (ushort_t*)(ws + offXt + xtBytes);   // (B*N, 1024) bf16
    // fbuf/sbuf alias the (dead after gemm1) Xt region
    size_t o0 = offXt;
    ushort_t* fbuf = (ushort_t*)(ws + o0);  o0 += (size_t)B_ * D_ * N_ * 2;
    float*    sbuf = (float*)(ws + o0);     o0 += (size_t)B_ * K_ * N_ * 4;

    prep_kernel<<<dim3(TRB2_ + CVB4_), 256, 0, stream>>>(
        x, w1c, b1c, w2c, b2c, w1s, b1s, w2s, b2s, temp, Xt, Wb, Tp);
    gemm1_kernel<<<dim3(1152), 256, 0, stream>>>(Xt, Wb, Wb + OB1_, h);
    gemm2_kernel<<<dim3(5, B_, 2), 256, 0, stream>>>(Wb, h, fbuf, sbuf);
    tail_kernel<<<dim3(B_), 512, 0, stream>>>(fbuf, sbuf, Tp, temp, (void*)d_out);
}

// Round 8
// 290.014 us; speedup vs baseline: 1.2808x; 1.2808x over previous
//
#include <hip/hip_runtime.h>

typedef unsigned short ushort_t;
typedef float f32x4 __attribute__((ext_vector_type(4)));
typedef short short8 __attribute__((ext_vector_type(8)));

#define B_   32
#define C_   1536
#define N_   576      // H*W = 24*24
#define HID_ 512
#define D_   128
#define K_   64

__device__ __forceinline__ float bf2f(ushort_t u) {
    union { unsigned u; float f; } c; c.u = ((unsigned)u) << 16; return c.f;
}
__device__ __forceinline__ ushort_t f2bf(float x) {
    unsigned u = __float_as_uint(x);
    return (ushort_t)((u + 0x7FFFu + ((u >> 16) & 1u)) >> 16);
}

// async global->LDS, 16B per lane. LDS dest = wave-uniform base + lane*16.
typedef const __attribute__((address_space(1))) char gas_char;
typedef __attribute__((address_space(3))) char las_char;
__device__ __forceinline__ void cp16(const void* g, void* l) {
    __builtin_amdgcn_global_load_lds((gas_char*)(size_t)g,
                                     (las_char*)(unsigned)(size_t)l, 16, 0, 0);
}
// raw barrier with compile-time memory fences (no vmcnt/lgkm drain!)
__device__ __forceinline__ void bar() {
    asm volatile("" ::: "memory");
    __builtin_amdgcn_s_barrier();
    asm volatile("" ::: "memory");
}

// Wb layout: W1cat (1024,1536) = [w1c;w1s] | b1cat (1024) | w2c | b2c | w2s | b2s
#define OB1_  1572864
#define OW2C_ 1573888
#define OB2C_ 1639424
#define OW2S_ 1639552
#define OB2S_ 1672320
#define WTOT_ 1672384
#define TRB2_ 3456                       // 12*9*32 transpose blocks (128c x 64n)
#define CVB4_ (((WTOT_ / 4) + 255) / 256)

// ---------------------------------------------------------------- prep
// Transpose x (B,C,N) -> Xt (B,N,C) bf16 with 128(C)x64(N) tiles.
__global__ __launch_bounds__(256) void prep_kernel(
    const void* __restrict__ x,
    const void* __restrict__ w1c, const void* __restrict__ b1c,
    const void* __restrict__ w2c, const void* __restrict__ b2c,
    const void* __restrict__ w1s, const void* __restrict__ b1s,
    const void* __restrict__ w2s, const void* __restrict__ b2s,
    const unsigned* __restrict__ temp,
    ushort_t* __restrict__ xt, ushort_t* __restrict__ o, float* __restrict__ Tp)
{
    __shared__ ushort_t t[128][65];
    unsigned d = temp[0];
    int flag = (d == 0x3F800000u) ? 1 : 0;
    int tid = threadIdx.x;
    int idx = blockIdx.x;
    if (idx == 0 && tid == 0)
        *Tp = flag ? __uint_as_float(d) : bf2f((ushort_t)(d & 0xFFFFu));

    if (idx < TRB2_) {
        int b = idx / 108, rem = idx % 108;
        int c0 = (rem % 12) * 128, n0 = (rem / 12) * 64;
        ushort_t* xtb = xt + (size_t)b * N_ * C_;
        int r = tid >> 4, n4 = (tid & 15) * 4;
        if (flag) {
            const float* xb = (const float*)x + (size_t)b * C_ * N_;
#pragma unroll
            for (int i = 0; i < 8; ++i) {
                int cc = r + i * 16;
                float4 v = *(const float4*)&xb[(size_t)(c0 + cc) * N_ + n0 + n4];
                t[cc][n4 + 0] = f2bf(v.x);
                t[cc][n4 + 1] = f2bf(v.y);
                t[cc][n4 + 2] = f2bf(v.z);
                t[cc][n4 + 3] = f2bf(v.w);
            }
        } else {
            const ushort_t* xb = (const ushort_t*)x + (size_t)b * C_ * N_;
#pragma unroll
            for (int i = 0; i < 8; ++i) {
                int cc = r + i * 16;
                *(uint2*)&t[cc][n4] =
                    *(const uint2*)&xb[(size_t)(c0 + cc) * N_ + n0 + n4];
            }
        }
        __syncthreads();
        int c8 = (tid & 15) * 8;
#pragma unroll
        for (int i = 0; i < 4; ++i) {
            int nn = r + i * 16;
            ushort_t vv[8];
#pragma unroll
            for (int j = 0; j < 8; ++j) vv[j] = t[c8 + j][nn];
            uint4 o4;
            o4.x = (unsigned)vv[0] | ((unsigned)vv[1] << 16);
            o4.y = (unsigned)vv[2] | ((unsigned)vv[3] << 16);
            o4.z = (unsigned)vv[4] | ((unsigned)vv[5] << 16);
            o4.w = (unsigned)vv[6] | ((unsigned)vv[7] << 16);
            *(uint4*)&xtb[(size_t)(n0 + nn) * C_ + c0 + c8] = o4;
        }
    } else {
        int i4 = ((idx - TRB2_) * 256 + tid) * 4;
        if (i4 >= WTOT_) return;
        const void* p; int off;
        if      (i4 < 786432)  { p = w1c; off = i4; }
        else if (i4 < OB1_)    { p = w1s; off = i4 - 786432; }
        else if (i4 < 1573376) { p = b1c; off = i4 - OB1_; }
        else if (i4 < OW2C_)   { p = b1s; off = i4 - 1573376; }
        else if (i4 < OB2C_)   { p = w2c; off = i4 - OW2C_; }
        else if (i4 < OW2S_)   { p = b2c; off = i4 - OB2C_; }
        else if (i4 < OB2S_)   { p = w2s; off = i4 - OW2S_; }
        else                   { p = b2s; off = i4 - OB2S_; }
        if (flag) {
            float4 v = *(const float4*)((const float*)p + off);
            uint2 r;
            r.x = (unsigned)f2bf(v.x) | ((unsigned)f2bf(v.y) << 16);
            r.y = (unsigned)f2bf(v.z) | ((unsigned)f2bf(v.w) << 16);
            *(uint2*)&o[i4] = r;
        } else {
            *(uint2*)&o[i4] = *(const uint2*)((const ushort_t*)p + off);
        }
    }
}

// ---------------------------------------------------------------- gemm1
// REVERTED to round-4/5 proven config (best measured): 128x128 tile,
// BK=64, 24 K-steps fully unrolled, 2-phase dbuf, counted vmcnt(8),
// XOR-swizzle, all staging through cp16.
__global__ __launch_bounds__(256) void gemm1_kernel(
    const ushort_t* __restrict__ Xt, const ushort_t* __restrict__ W1,
    const ushort_t* __restrict__ bias, ushort_t* __restrict__ h)
{
    __shared__ ushort_t Atile[2][128 * 64];   // 32 KB
    __shared__ ushort_t Btile[2][128 * 64];   // 32 KB
    int idx = blockIdx.x;
    int l = (idx & 7) * 144 + (idx >> 3);    // XCD-chunked logical id
    int mt = l >> 3, t = l & 7;
    int row0 = mt * 128, col0 = t * 128;

    int tid = threadIdx.x, w = tid >> 6, lane = tid & 63;
    int wr = w >> 1, wc = w & 1;
    int r16 = lane & 15, q = lane >> 4, kh = q * 8;

    int srow = tid >> 3;
    int cx = ((tid & 7) ^ (srow & 7)) * 8;   // pre-swizzled source col (elems)
    const ushort_t* ag[4];
    const ushort_t* bg[4];
#pragma unroll
    for (int s = 0; s < 4; ++s) {
        ag[s] = Xt + (size_t)(row0 + s * 32 + srow) * C_ + cx;
        bg[s] = W1 + (size_t)(col0 + s * 32 + srow) * C_ + cx;
    }

    f32x4 acc[4][4];
#pragma unroll
    for (int i = 0; i < 4; ++i)
#pragma unroll
        for (int j = 0; j < 4; ++j) acc[i][j] = f32x4{0.f, 0.f, 0.f, 0.f};

    int rowa = wr * 64 + r16;
    int rowb = wc * 64 + r16;
    int xr = (r16 & 7) * 8;                  // read-side XOR (elems)

    auto stage = [&](int buf, int koff) {
#pragma unroll
        for (int s = 0; s < 4; ++s) {
            cp16(ag[s] + koff, &Atile[buf][tid * 8 + s * 2048]);
            cp16(bg[s] + koff, &Btile[buf][tid * 8 + s * 2048]);
        }
    };
    auto compute = [&](int cb) {
#pragma unroll
        for (int ks = 0; ks < 2; ++ks) {
            int ke = (ks * 32 + kh) ^ xr;
            short8 af[4], bf[4];
#pragma unroll
            for (int i = 0; i < 4; ++i)
                af[i] = *(const short8*)&Atile[cb][(rowa + i * 16) * 64 + ke];
#pragma unroll
            for (int j = 0; j < 4; ++j)
                bf[j] = *(const short8*)&Btile[cb][(rowb + j * 16) * 64 + ke];
#pragma unroll
            for (int i = 0; i < 4; ++i)
#pragma unroll
                for (int j = 0; j < 4; ++j)
                    acc[i][j] = __builtin_amdgcn_mfma_f32_16x16x32_bf16(
                        af[i], bf[j], acc[i][j], 0, 0, 0);
        }
    };

    stage(0, 0);
#pragma unroll
    for (int kt = 0; kt < 24; ++kt) {
        int buf = kt & 1;
        if (kt < 23) {
            stage(buf ^ 1, (kt + 1) * 64);
            asm volatile("s_waitcnt vmcnt(8)" ::: "memory");
        } else {
            asm volatile("s_waitcnt vmcnt(0)" ::: "memory");
        }
        bar();
        compute(buf);
        bar();
    }

#pragma unroll
    for (int j = 0; j < 4; ++j) {
        int col = col0 + wc * 64 + j * 16 + r16;
        float cb = bf2f(bias[col]);
#pragma unroll
        for (int i = 0; i < 4; ++i) {
            int rowo = row0 + wr * 64 + i * 16 + q * 4;
#pragma unroll
            for (int r = 0; r < 4; ++r) {
                float v = fmaxf(acc[i][j][r] + cb, 0.f);
                h[(size_t)(rowo + r) * 1024 + col] = f2bf(v);
            }
        }
    }
}

// ---------------------------------------------------------------- gemm2
// Restructured: grid (5, B, 3), 64-row tiles -> zero M-waste (old z=1
// tile clamp-duplicated rows 64-127 = 25% wasted MFMA). z=0,1: f rows
// 0-63 / 64-127 (w2c); z=2: s rows 0-63 (w2s). Same proven 2-phase dbuf
// skeleton, 3 cp16/step, vmcnt(3), 16 K-steps unrolled.
__global__ __launch_bounds__(256) void gemm2_kernel(
    const ushort_t* __restrict__ Wb, const ushort_t* __restrict__ h,
    ushort_t* __restrict__ fbuf, float* __restrict__ sbuf)
{
    __shared__ ushort_t Atile[2][64 * 32];    // 4 KB each
    __shared__ ushort_t Btile[2][128 * 32];   // 8 KB each
    int nt = blockIdx.x, b = blockIdx.y, z = blockIdx.z;
    int col0 = nt * 128;
    const ushort_t* Aw   = Wb + (z == 2 ? OW2S_ : OW2C_ + z * 64 * HID_);
    const ushort_t* bias = Wb + (z == 2 ? OB2S_ : OB2C_ + z * 64);
    const ushort_t* hb = h + (size_t)b * N_ * 1024 + (z == 2 ? 512 : 0);

    int tid = threadIdx.x, w = tid >> 6, lane = tid & 63;
    int wr = w >> 1, wc = w & 1;
    int r16 = lane & 15, q = lane >> 4, kh = q * 8;

    int srow = tid >> 2;
    int swz = ((tid & 3) ^ (srow & 3)) * 8;
    const ushort_t* ag0 = Aw + (size_t)srow * HID_ + swz;     // 64 A rows
    int br0 = min(col0 + srow, N_ - 1);
    int br1 = min(col0 + 64 + srow, N_ - 1);
    const ushort_t* bg0 = hb + (size_t)br0 * 1024 + swz;
    const ushort_t* bg1 = hb + (size_t)br1 * 1024 + swz;

    f32x4 acc[2][4];
#pragma unroll
    for (int i = 0; i < 2; ++i)
#pragma unroll
        for (int j = 0; j < 4; ++j) acc[i][j] = f32x4{0.f, 0.f, 0.f, 0.f};

    int xr = (r16 & 3) * 8;

    auto stage = [&](int buf, int koff) {
        cp16(ag0 + koff, &Atile[buf][tid * 8]);
        cp16(bg0 + koff, &Btile[buf][tid * 8]);
        cp16(bg1 + koff, &Btile[buf][2048 + tid * 8]);
    };
    auto compute = [&](int cb) {
        int ke = kh ^ xr;
        short8 af[2], bf[4];
#pragma unroll
        for (int i = 0; i < 2; ++i)
            af[i] = *(const short8*)&Atile[cb][(wr * 32 + i * 16 + r16) * 32 + ke];
#pragma unroll
        for (int j = 0; j < 4; ++j)
            bf[j] = *(const short8*)&Btile[cb][(wc * 64 + j * 16 + r16) * 32 + ke];
#pragma unroll
        for (int i = 0; i < 2; ++i)
#pragma unroll
            for (int j = 0; j < 4; ++j)
                acc[i][j] = __builtin_amdgcn_mfma_f32_16x16x32_bf16(
                    af[i], bf[j], acc[i][j], 0, 0, 0);
    };

    stage(0, 0);
#pragma unroll
    for (int kt = 0; kt < 16; ++kt) {
        int buf = kt & 1;
        if (kt < 15) {
            stage(buf ^ 1, (kt + 1) * 32);
            asm volatile("s_waitcnt vmcnt(3)" ::: "memory");
        } else {
            asm volatile("s_waitcnt vmcnt(0)" ::: "memory");
        }
        bar();
        compute(buf);
        bar();
    }

#pragma unroll
    for (int j = 0; j < 4; ++j) {
        int col = col0 + wc * 64 + j * 16 + r16;
        if (col >= N_) continue;
#pragma unroll
        for (int i = 0; i < 2; ++i) {
            int rowb = wr * 32 + i * 16 + q * 4;
#pragma unroll
            for (int r = 0; r < 4; ++r) {
                int rr = rowb + r;                    // 0..63 within tile
                float v = acc[i][j][r] + bf2f(bias[rr]);
                if (z == 2)
                    sbuf[(size_t)b * K_ * N_ + (size_t)rr * N_ + col] = v;
                else
                    fbuf[(size_t)b * D_ * N_ +
                         (size_t)(z * 64 + rr) * N_ + col] = f2bf(v);
            }
        }
    }
}

// ---------------------------------------------------------------- tail
// One block per batch (512 thr). Fused sinkhorn + aggregation + L2 norm.
__global__ __launch_bounds__(512) void tail_kernel(
    const ushort_t* __restrict__ f_all, const float* __restrict__ s_all,
    const float* __restrict__ Tp, const unsigned* __restrict__ temp,
    void* __restrict__ out)
{
    __shared__ float Sl[K_ * 577];   // 147,712 B
    __shared__ float su[K_];
    __shared__ float sv[N_];
    __shared__ float red[8];
    ushort_t* Plds = (ushort_t*)Sl;                       // [0, 74,752)
    ushort_t* At0  = (ushort_t*)((char*)Sl + 81920);      // 16 KB
    ushort_t* At1  = (ushort_t*)((char*)Sl + 81920 + 16384);

    int b = blockIdx.x;
    int tid = threadIdx.x, w = tid >> 6, lane = tid & 63;
    const float norm = -logf((float)N_);

    // ---- load S into LDS (coalesced float4)
    const float4* S4 = (const float4*)(s_all + (size_t)b * K_ * N_);
    for (int g = tid; g < (K_ * N_) / 4; g += 512) {
        float4 v = S4[g];
        int w0 = g * 4;
        int r = w0 / N_;
        int base = w0 + r;           // == r*577 + (w0 - r*576)
        Sl[base + 0] = v.x; Sl[base + 1] = v.y;
        Sl[base + 2] = v.z; Sl[base + 3] = v.w;
    }
    for (int n = tid; n < N_; n += 512) sv[n] = 0.f;
    __syncthreads();

    // ---- 3 sinkhorn iterations
    for (int it = 0; it < 3; ++it) {
        for (int r = w; r < K_; r += 8) {
            const float* Sr = Sl + r * 577;
            float a0 = 0.f, a1 = 0.f, a2 = 0.f;
#pragma unroll
            for (int k = 0; k < 9; k += 3) {
                int n0 = lane + 64 * k;
                a0 += __expf(Sr[n0] + sv[n0]);
                a1 += __expf(Sr[n0 + 64] + sv[n0 + 64]);
                a2 += __expf(Sr[n0 + 128] + sv[n0 + 128]);
            }
            float t = a0 + a1 + a2;
#pragma unroll
            for (int off = 32; off; off >>= 1) t += __shfl_xor(t, off);
            if (lane == 0) su[r] = norm - __logf(t);
        }
        __syncthreads();
        for (int n = tid; n < N_; n += 512) {
            const float* Sc = Sl + n;
            float a0 = 0.f, a1 = 0.f, a2 = 0.f, a3 = 0.f;
#pragma unroll
            for (int m = 0; m < K_; m += 4) {
                a0 += __expf(Sc[(m + 0) * 577] + su[m + 0]);
                a1 += __expf(Sc[(m + 1) * 577] + su[m + 1]);
                a2 += __expf(Sc[(m + 2) * 577] + su[m + 2]);
                a3 += __expf(Sc[(m + 3) * 577] + su[m + 3]);
            }
            sv[n] = norm - __logf((a0 + a1) + (a2 + a3));
        }
        __syncthreads();
    }

    // ---- P into regs (wave w owns rows 8w..8w+7), barrier, pack into LDS
    float invT = 1.f / (*Tp);
    ushort_t pv[8][9];
#pragma unroll
    for (int rr = 0; rr < 8; ++rr) {
        int r = w * 8 + rr;
        float ur = su[r];
        const float* Sr = Sl + r * 577;
#pragma unroll
        for (int k = 0; k < 9; ++k) {
            int n0 = lane + 64 * k;
            float lp = Sr[n0] + ur + sv[n0] - norm;
            pv[rr][k] = f2bf(__expf(lp * invT) + __expf(lp));
        }
    }
    __syncthreads();   // all S reads complete before overwriting with P
#pragma unroll
    for (int rr = 0; rr < 8; ++rr) {
        int r = w * 8 + rr;
#pragma unroll
        for (int k = 0; k < 9; ++k)
            Plds[r * 584 + lane + 64 * k] = pv[rr][k];
    }
    __syncthreads();   // P visible to all waves (full lgkm drain)

    // ---- agg GEMM: 9 steps BK=64, dbuf F staging, P in place
    int wr = w >> 2, wc = w & 3;
    int r16 = lane & 15, q = lane >> 4, kh = q * 8;
    const ushort_t* F = f_all + (size_t)b * D_ * N_;
    int srow = tid >> 3;                      // 0..63
    int cx = ((tid & 7) ^ (srow & 7)) * 8;    // pre-swizzled source col
    const ushort_t* fg0 = F + (size_t)srow * N_ + cx;
    const ushort_t* fg1 = F + (size_t)(64 + srow) * N_ + cx;

    f32x4 acc[4];
#pragma unroll
    for (int i = 0; i < 4; ++i) acc[i] = f32x4{0.f, 0.f, 0.f, 0.f};

    int rowa = wr * 64 + r16;
    int prow = wc * 16 + r16;
    int xr = (r16 & 7) * 8;

    auto stageF = [&](ushort_t* At, int koff) {
        cp16(fg0 + koff, At + tid * 8);
        cp16(fg1 + koff, At + 4096 + tid * 8);
    };
    auto computeT = [&](const ushort_t* At, int s) {
#pragma unroll
        for (int ks = 0; ks < 2; ++ks) {
            int ke = (ks * 32 + kh) ^ xr;
            short8 af[4];
#pragma unroll
            for (int i = 0; i < 4; ++i)
                af[i] = *(const short8*)&At[(rowa + i * 16) * 64 + ke];
            short8 pf = *(const short8*)&Plds[prow * 584 + s * 64 + ks * 32 + kh];
#pragma unroll
            for (int i = 0; i < 4; ++i)
                acc[i] = __builtin_amdgcn_mfma_f32_16x16x32_bf16(
                    af[i], pf, acc[i], 0, 0, 0);
        }
    };

    stageF(At0, 0);
#pragma unroll
    for (int kt = 0; kt < 9; ++kt) {
        ushort_t* cb = (kt & 1) ? At1 : At0;
        ushort_t* nb = (kt & 1) ? At0 : At1;
        if (kt < 8) {
            stageF(nb, (kt + 1) * 64);
            asm volatile("s_waitcnt vmcnt(2)" ::: "memory");
        } else {
            asm volatile("s_waitcnt vmcnt(0)" ::: "memory");
        }
        bar();
        computeT(cb, kt);
        bar();
    }

    // ---- block-wide L2 norm + store
    float ssq = 0.f;
#pragma unroll
    for (int i = 0; i < 4; ++i)
#pragma unroll
        for (int r = 0; r < 4; ++r) { float v = acc[i][r]; ssq += v * v; }
#pragma unroll
    for (int off = 32; off; off >>= 1) ssq += __shfl_xor(ssq, off);
    if (lane == 0) red[w] = ssq;
    __syncthreads();
    float tot = (red[0] + red[1] + red[2] + red[3])
              + (red[4] + red[5] + red[6] + red[7]);
    float inv = 1.f / fmaxf(sqrtf(tot), 1e-12f);
    int flag = (temp[0] == 0x3F800000u) ? 1 : 0;
#pragma unroll
    for (int i = 0; i < 4; ++i) {
        int col = wc * 16 + r16;
#pragma unroll
        for (int r = 0; r < 4; ++r) {
            int row = wr * 64 + i * 16 + q * 4 + r;
            float v = acc[i][r] * inv;
            size_t idx = (size_t)b * D_ * K_ + (size_t)row * K_ + col;
            if (flag) ((float*)out)[idx] = v;
            else      ((ushort_t*)out)[idx] = f2bf(v);
        }
    }
}

extern "C" void kernel_launch(void* const* d_in, const int* in_sizes, int n_in,
                              void* d_out, int out_size, void* d_ws, size_t ws_size,
                              hipStream_t stream) {
    const void* x    = d_in[0];
    const void* w1c  = d_in[1];
    const void* b1c  = d_in[2];
    const void* w2c  = d_in[3];
    const void* b2c  = d_in[4];
    const void* w1s  = d_in[5];
    const void* b1s  = d_in[6];
    const void* w2s  = d_in[7];
    const void* b2s  = d_in[8];
    const unsigned* temp = (const unsigned*)d_in[9];

    char* ws = (char*)d_ws;
    float* Tp = (float*)ws;
    ushort_t* Wb = (ushort_t*)(ws + 256);
    size_t offXt = 256 + (((size_t)WTOT_ * 2 + 255) & ~(size_t)255);
    ushort_t* Xt = (ushort_t*)(ws + offXt);
    size_t xtBytes = (size_t)B_ * N_ * C_ * 2;
    ushort_t* h  = (ushort_t*)(ws + offXt + xtBytes);   // (B*N, 1024) bf16
    // fbuf/sbuf alias the (dead after gemm1) Xt region
    size_t o0 = offXt;
    ushort_t* fbuf = (ushort_t*)(ws + o0);  o0 += (size_t)B_ * D_ * N_ * 2;
    float*    sbuf = (float*)(ws + o0);     o0 += (size_t)B_ * K_ * N_ * 4;

    prep_kernel<<<dim3(TRB2_ + CVB4_), 256, 0, stream>>>(
        x, w1c, b1c, w2c, b2c, w1s, b1s, w2s, b2s, temp, Xt, Wb, Tp);
    gemm1_kernel<<<dim3(1152), 256, 0, stream>>>(Xt, Wb, Wb + OB1_, h);
    gemm2_kernel<<<dim3(5, B_, 3), 256, 0, stream>>>(Wb, h, fbuf, sbuf);
    tail_kernel<<<dim3(B_), 512, 0, stream>>>(fbuf, sbuf, Tp, temp, (void*)d_out);
}